// Round 1
// baseline (22980.435 us; speedup 1.0000x reference)
//
#include <hip/hip_runtime.h>
#include <math.h>
#include <stdint.h>

// ============================================================================
// TopDownNet via split-f16 MFMA (R5 rewrite).
// fp32 path was VALU-bound at 54% of the 157 TF vector peak (MfmaUtil=0).
// Each fp32 GEMM is computed with 3 f16 MFMAs (16x16x32):
//   x = xh + xl*2^-11,  w = wh + wl*2^-11   (xl=(x-xh)*2048 stays f16-normal)
//   acc1 += xh*wh ; acc2 += xh*wl + xl*wh ; result = acc1 + acc2/2048
// dropped xl*wl ~ 2^-22 rel -> absmax ~1e-6 vs 2.2e-5 threshold.
//
// Fragment layouts (gfx950, 16x16x32): A: row=l&15, k=(l>>4)*8+i
//   B: col=l&15, k=(l>>4)*8+i ; D: row=(l>>4)*4+r, col=l&15.
// All layers are computed SWAPPED: D[of][sample] = W^T X^T, so activations are
// the B operand with sample = l&15, read from a per-wave LDS buffer of packed
// u32 (f16 hi | f16 lo<<16) per feature. W^T fragments are pre-shuffled by
// prep_w into per-lane dwordx4 streams. M-layers bounce through LDS in place;
// O1->O2 stays in registers via ds_bpermute; O3+sigmoid folded into O2 epilogue.
// ============================================================================

typedef _Float16 half8 __attribute__((ext_vector_type(8)));
typedef float f32x4 __attribute__((ext_vector_type(4)));

constexpr int KS = 10;
constexpr int XSTR = 292;   // u32 per sample row (288 feats + 4 pad; 292%32=4 -> spread banks)
constexpr float SPLIT_S = 2048.f;
constexpr float SPLIT_INV = 1.f / 2048.f;

// W^T fragment streams. Global frag idx: O1 0-143 (9 chunks), M1 144-287,
// O2 288-415, M2 416-543, M3 544-671. Frag = 64 lanes * 8 f16 (16B/lane).
__device__ __align__(16) _Float16 g_Wh[672 * 512];
__device__ __align__(16) _Float16 g_Wl[672 * 512];

__global__ void prep_w(const float* __restrict__ O1w, const float* __restrict__ M1w,
                       const float* __restrict__ O2w, const float* __restrict__ M2w,
                       const float* __restrict__ M3w) {
  const int bid = blockIdx.x, l = threadIdx.x;
  const float* W; int Ksrc, f;
  if (bid < 144)      { W = O1w; Ksrc = 270; f = bid; }
  else if (bid < 288) { W = M1w; Ksrc = 270; f = bid - 144; }
  else if (bid < 416) { W = O2w; Ksrc = 256; f = bid - 288; }
  else if (bid < 544) { W = M2w; Ksrc = 256; f = bid - 416; }
  else                { W = M3w; Ksrc = 256; f = bid - 544; }
  const int c = f >> 4, nt = f & 15, g = l >> 4, s = l & 15;
  const int of = nt * 16 + s;     // output feature (A-operand m-index = l&15)
  union { half8 h; uint4 u; } hv, lv;
#pragma unroll
  for (int i = 0; i < 8; ++i) {
    const int k = c * 32 + g * 8 + i;               // input-feature (K) index
    const float w = (k < Ksrc) ? W[k * 256 + of] : 0.f;  // zero-pad rows 270..287
    const _Float16 h = (_Float16)w;
    hv.h[i] = h;
    lv.h[i] = (_Float16)((w - (float)h) * SPLIT_S);
  }
  ((uint4*)g_Wh)[bid * 64 + l] = hv.u;
  ((uint4*)g_Wl)[bid * 64 + l] = lv.u;
}

__device__ __forceinline__ half8 as_half8(uint4 u) {
  union { uint4 u4; half8 h; } c; c.u4 = u; return c.h;
}
__device__ __forceinline__ f32x4 mfma16(half8 a, half8 b, f32x4 c) {
  return __builtin_amdgcn_mfma_f32_16x16x32_f16(a, b, c, 0, 0, 0);
}
__device__ __forceinline__ uint32_t bp(int idx, uint32_t v) {
  return (uint32_t)__builtin_amdgcn_ds_bpermute(idx, (int)v);
}
// packed feature word: low16 = f16 hi part, high16 = f16 scaled-lo part
__device__ __forceinline__ uint32_t pack_feat(float v) {
  _Float16 h = (_Float16)v;
  _Float16 lo = (_Float16)((v - (float)h) * SPLIT_S);
  union { _Float16 h2[2]; uint32_t u; } p; p.h2[0] = h; p.h2[1] = lo; return p.u;
}
__device__ __forceinline__ void split2(float a, float b, uint32_t& hw, uint32_t& lw) {
  _Float16 ah = (_Float16)a, bh = (_Float16)b;
  _Float16 al = (_Float16)((a - (float)ah) * SPLIT_S);
  _Float16 bl = (_Float16)((b - (float)bh) * SPLIT_S);
  union { _Float16 h2[2]; uint32_t u; } p;
  p.h2[0] = ah; p.h2[1] = bh; hw = p.u;
  p.h2[0] = al; p.h2[1] = bl; lw = p.u;
}
// B-frag from 8 consecutive packed u32 (features c*32+8g .. +7 of sample s)
__device__ __forceinline__ void unpack_bfrag(const uint32_t* __restrict__ xp,
                                             half8& bh, half8& bl) {
  uint4 x0 = *(const uint4*)xp;
  uint4 x1 = *(const uint4*)(xp + 4);
  union { uint32_t u[4]; half8 h; } H, L;
  H.u[0] = (x0.x & 0xffffu) | (x0.y << 16);
  H.u[1] = (x0.z & 0xffffu) | (x0.w << 16);
  H.u[2] = (x1.x & 0xffffu) | (x1.y << 16);
  H.u[3] = (x1.z & 0xffffu) | (x1.w << 16);
  L.u[0] = (x0.x >> 16) | (x0.y & 0xffff0000u);
  L.u[1] = (x0.z >> 16) | (x0.w & 0xffff0000u);
  L.u[2] = (x1.x >> 16) | (x1.y & 0xffff0000u);
  L.u[3] = (x1.z >> 16) | (x1.w & 0xffff0000u);
  bh = H.h; bl = L.h;
}
__device__ __forceinline__ void zero16(f32x4* a, f32x4* b) {
#pragma unroll
  for (int z = 0; z < 16; ++z) {
    a[z] = (f32x4){0.f, 0.f, 0.f, 0.f};
    b[z] = (f32x4){0.f, 0.f, 0.f, 0.f};
  }
}

// swapped GEMM over CHUNKS K-chunks of 32: acc{1,2}[nt] over 16 of-tiles.
// c-loop deliberately NOT unrolled (I$ budget: whole k-body must stay < 32KB).
template <int CHUNKS>
__device__ __forceinline__ void layer_gemm(f32x4 acc1[16], f32x4 acc2[16],
                                           const uint32_t* __restrict__ Xw,
                                           const uint4* __restrict__ Wh,
                                           const uint4* __restrict__ Wl,
                                           int s, int g) {
#pragma unroll 1
  for (int c = 0; c < CHUNKS; ++c) {
    half8 bh, bl;
    unpack_bfrag(Xw + s * XSTR + c * 32 + g * 8, bh, bl);
#pragma unroll
    for (int nt = 0; nt < 16; ++nt) {
      half8 wh = as_half8(Wh[(c * 16 + nt) * 64]);
      half8 wl = as_half8(Wl[(c * 16 + nt) * 64]);
      acc1[nt] = mfma16(wh, bh, acc1[nt]);
      acc2[nt] = mfma16(wh, bl, acc2[nt]);
      acc2[nt] = mfma16(wl, bh, acc2[nt]);
    }
  }
}

// epilogue: v = relu(acc1 + acc2/2048 + bias); write packed to LDS (in place,
// safe: all B-frag reads of this buffer completed before first write).
__device__ __forceinline__ void epi_write(const f32x4* acc1, const f32x4* acc2,
                                          const float* __restrict__ bias,
                                          uint32_t* __restrict__ Xw, int s, int g) {
#pragma unroll
  for (int nt = 0; nt < 16; ++nt) {
    const float4 bv = *(const float4*)(bias + nt * 16 + g * 4);
    float v0 = fmaxf(fmaf(acc2[nt][0], SPLIT_INV, acc1[nt][0]) + bv.x, 0.f);
    float v1 = fmaxf(fmaf(acc2[nt][1], SPLIT_INV, acc1[nt][1]) + bv.y, 0.f);
    float v2 = fmaxf(fmaf(acc2[nt][2], SPLIT_INV, acc1[nt][2]) + bv.z, 0.f);
    float v3 = fmaxf(fmaf(acc2[nt][3], SPLIT_INV, acc1[nt][3]) + bv.w, 0.f);
    uint32_t* xp = Xw + s * XSTR + nt * 16 + g * 4;   // feature 16nt+4g+r
    *(uint2*)xp       = make_uint2(pack_feat(v0), pack_feat(v1));
    *(uint2*)(xp + 2) = make_uint2(pack_feat(v2), pack_feat(v3));
  }
}

// O2 B-frag gather from h1 register pk-arrays (cc must be a compile-time const)
#define GATHER(dst, P01, P23, cc)                                              \
  do {                                                                         \
    union { uint32_t u[4]; half8 h; } B_;                                      \
    uint32_t e_, o_;                                                           \
    e_ = bp(srcA, P01[2 * (cc)]); o_ = bp(srcA, P01[2 * (cc) + 1]);            \
    B_.u[0] = g2 ? o_ : e_;                                                    \
    e_ = bp(srcA, P23[2 * (cc)]); o_ = bp(srcA, P23[2 * (cc) + 1]);            \
    B_.u[1] = g2 ? o_ : e_;                                                    \
    e_ = bp(srcB, P01[2 * (cc)]); o_ = bp(srcB, P01[2 * (cc) + 1]);            \
    B_.u[2] = g2 ? o_ : e_;                                                    \
    e_ = bp(srcB, P23[2 * (cc)]); o_ = bp(srcB, P23[2 * (cc) + 1]);            \
    B_.u[3] = g2 ? o_ : e_;                                                    \
    dst = B_.h;                                                                \
  } while (0)

__global__ __launch_bounds__(128, 2) void topdown_mfma(
    const float* __restrict__ towers, const float* __restrict__ aggregate,
    const float* __restrict__ O1b, const float* __restrict__ O2b,
    const float* __restrict__ O3w, const float* __restrict__ O3b,
    const float* __restrict__ M1b, const float* __restrict__ M2b,
    const float* __restrict__ M3b, float* __restrict__ out) {
  __shared__ uint32_t sm[2 * 16 * XSTR];   // 37376 B -> 4 blocks/CU, 2 waves/SIMD
  const int t = threadIdx.x, w = t >> 6, l = t & 63;
  const int g = l >> 4, s = l & 15;
  const bool g2 = (g & 2) != 0;
  uint32_t* Xw = sm + w * 16 * XSTR;
  const int n0 = blockIdx.x * 32 + w * 16;

  const uint4* WhL = (const uint4*)g_Wh + l;
  const uint4* WlL = (const uint4*)g_Wl + l;

  // init X: features 0..255 = aggregate (broadcast across samples); 270..287 = 0
  for (int idx = l; idx < 16 * 256; idx += 64)
    Xw[(idx & 15) * XSTR + (idx >> 4)] = pack_feat(aggregate[idx >> 4]);
  for (int idx = l; idx < 16 * 18; idx += 64)
    Xw[(idx & 15) * XSTR + 270 + (idx >> 4)] = 0u;

  float prod = 1.f;
  const float o3bias = O3b[0];
  f32x4 acc1[16], acc2[16];

  for (int kk = 0; kk < KS; ++kk) {
    const int tbase = (KS - 1 - kk) * 14;   // reference flips along K
    // tower slice -> features 256..269
#pragma unroll
    for (int j = 0; j < 4; ++j) {
      const int e = l + 64 * j;
      if (e < 224) {
        const int ss = e & 15, f = e >> 4;
        Xw[ss * XSTR + 256 + f] = pack_feat(towers[(n0 + ss) * (KS * 14) + tbase + f]);
      }
    }
    __syncthreads();   // pacing only (keeps both waves' weight streams L1-coherent)

    // ---------------- O1: h1 stays in registers (pk arrays)
    zero16(acc1, acc2);
    layer_gemm<9>(acc1, acc2, Xw, WhL, WlL, s, g);
    uint32_t pkh01[16], pkh23[16], pkl01[16], pkl23[16];
#pragma unroll
    for (int nt = 0; nt < 16; ++nt) {
      const float4 bv = *(const float4*)(O1b + nt * 16 + g * 4);
      float v0 = fmaxf(fmaf(acc2[nt][0], SPLIT_INV, acc1[nt][0]) + bv.x, 0.f);
      float v1 = fmaxf(fmaf(acc2[nt][1], SPLIT_INV, acc1[nt][1]) + bv.y, 0.f);
      float v2 = fmaxf(fmaf(acc2[nt][2], SPLIT_INV, acc1[nt][2]) + bv.z, 0.f);
      float v3 = fmaxf(fmaf(acc2[nt][3], SPLIT_INV, acc1[nt][3]) + bv.w, 0.f);
      split2(v0, v1, pkh01[nt], pkl01[nt]);
      split2(v2, v3, pkh23[nt], pkl23[nt]);
    }

    // ---------------- O2 (+O3 fold): B-frags gathered from pk via ds_bpermute.
    // h1[of][s] lives at lane 32*(g&1)+ (of&15>=8 ? 16:0) + s, nt0=2c+(g>>1).
    zero16(acc1, acc2);
    {
      const int srcA = (32 * (g & 1) + s) * 4, srcB = srcA + 64;
#pragma unroll
      for (int c = 0; c < 8; ++c) {
        half8 bh, bl;
        GATHER(bh, pkh01, pkh23, c);
        GATHER(bl, pkl01, pkl23, c);
#pragma unroll
        for (int nt = 0; nt < 16; ++nt) {
          half8 wh = as_half8(WhL[(288 * 16 + c * 16 + nt) * 64 - 288 * 16 * 64 + (288 + c * 16 + nt) * 0]);
          // (simplified below)
          wh = as_half8(WhL[(288 + c * 16 + nt) * 64]);
          half8 wl = as_half8(WlL[(288 + c * 16 + nt) * 64]);
          acc1[nt] = mfma16(wh, bh, acc1[nt]);
          acc2[nt] = mfma16(wh, bl, acc2[nt]);
          acc2[nt] = mfma16(wl, bh, acc2[nt]);
        }
      }
    }
    float tpart = 0.f;
#pragma unroll
    for (int nt = 0; nt < 16; ++nt) {
      const float4 bv = *(const float4*)(O2b + nt * 16 + g * 4);
      const float4 ov = *(const float4*)(O3w + nt * 16 + g * 4);
      tpart += fmaxf(fmaf(acc2[nt][0], SPLIT_INV, acc1[nt][0]) + bv.x, 0.f) * ov.x;
      tpart += fmaxf(fmaf(acc2[nt][1], SPLIT_INV, acc1[nt][1]) + bv.y, 0.f) * ov.y;
      tpart += fmaxf(fmaf(acc2[nt][2], SPLIT_INV, acc1[nt][2]) + bv.z, 0.f) * ov.z;
      tpart += fmaxf(fmaf(acc2[nt][3], SPLIT_INV, acc1[nt][3]) + bv.w, 0.f) * ov.w;
    }
    tpart += __shfl_xor(tpart, 16);
    tpart += __shfl_xor(tpart, 32);
    prod *= 1.f / (1.f + expf(-(tpart + o3bias)));

    // ---------------- M1 (reads X, then overwrites X in place)
    zero16(acc1, acc2);
    layer_gemm<9>(acc1, acc2, Xw, WhL + 144 * 64, WlL + 144 * 64, s, g);
    epi_write(acc1, acc2, M1b, Xw, s, g);
    // ---------------- M2
    zero16(acc1, acc2);
    layer_gemm<8>(acc1, acc2, Xw, WhL + 416 * 64, WlL + 416 * 64, s, g);
    epi_write(acc1, acc2, M2b, Xw, s, g);
    // ---------------- M3 (output = next step's summary)
    zero16(acc1, acc2);
    layer_gemm<8>(acc1, acc2, Xw, WhL + 544 * 64, WlL + 544 * 64, s, g);
    epi_write(acc1, acc2, M3b, Xw, s, g);
  }

  if (l < 16) out[n0 + l] = prod;   // lanes g==0 hold sample s=l; prod replicated
}

extern "C" void kernel_launch(void* const* d_in, const int* in_sizes, int n_in,
                              void* d_out, int out_size, void* d_ws, size_t ws_size,
                              hipStream_t stream) {
  const float* towers    = (const float*)d_in[0];
  const float* aggregate = (const float*)d_in[1];
  const float* M1w = (const float*)d_in[2];
  const float* M1b = (const float*)d_in[3];
  const float* M2w = (const float*)d_in[4];
  const float* M2b = (const float*)d_in[5];
  const float* M3w = (const float*)d_in[6];
  const float* M3b = (const float*)d_in[7];
  const float* O1w = (const float*)d_in[8];
  const float* O1b = (const float*)d_in[9];
  const float* O2w = (const float*)d_in[10];
  const float* O2b = (const float*)d_in[11];
  const float* O3w = (const float*)d_in[12];
  const float* O3b = (const float*)d_in[13];
  float* out = (float*)d_out;

  prep_w<<<672, 64, 0, stream>>>(O1w, M1w, O2w, M2w, M3w);

  const int nblocks = out_size / 32;   // 4096 blocks x 128 threads (2 waves)
  topdown_mfma<<<nblocks, 128, 0, stream>>>(towers, aggregate, O1b, O2b, O3w, O3b,
                                            M1b, M2b, M3b, out);
}

// Round 2
// 3135.120 us; speedup vs baseline: 7.3300x; 7.3300x over previous
//
#include <hip/hip_runtime.h>
#include <math.h>
#include <stdint.h>

// ============================================================================
// TopDownNet via split-f16 MFMA, R6: of-quarter split + planar LDS.
// R5 failed on (a) register spills (1.9 GB scratch writes) and (b) per-wave
// weight streaming (110 GB demand). R6: block = 4 waves x 64 samples; wave w
// owns output features [64w, 64w+64) for ALL 64 samples -> 4x less weight
// traffic; activations in LDS as separate hi/lo f16 planes -> B-frags are two
// ds_read_b128, no unpack VALU; O1->O2 through LDS (M1 result parked in 64
// packed regs); biases staged in LDS; reduction scratch overlaid in row pad.
// Register peak ~250 <= 256/wave budget for 2 waves/SIMD -> no spills.
//
// Split math (validated in R5, absmax 3.8e-6):
//   x = xh + xl*2^-11 (xl=(x-xh)*2048), same for w;
//   acc1 += xh*wh ; acc2 += xh*wl + xl*wh ; result = acc1 + acc2/2048.
// Fragment layouts (gfx950 16x16x32): A row=l&15 (of within tile),
//   k=(l>>4)*8+i ; B col=l&15 (sample), same k ; D row=(l>>4)*4+r, col=l&15.
// ============================================================================

typedef _Float16 half8 __attribute__((ext_vector_type(8)));
typedef float f32x4 __attribute__((ext_vector_type(4)));

constexpr int KS = 10;
constexpr int RSTR = 584;  // f16 per sample row: 288 hi + 288 lo + 8 pad(scratch)
constexpr float SPLIT_S = 2048.f;
constexpr float SPLIT_INV = 1.f / 2048.f;

// W^T fragment streams (unchanged from R5; verified correct).
// Frag idx: O1 0-143 (9 chunks x 16 nt), M1 144-287, O2 288-415, M2 416-543,
// M3 544-671. Frag = 64 lanes x 8 f16 (16 B/lane).
__device__ __align__(16) _Float16 g_Wh[672 * 512];
__device__ __align__(16) _Float16 g_Wl[672 * 512];

__global__ void prep_w(const float* __restrict__ O1w, const float* __restrict__ M1w,
                       const float* __restrict__ O2w, const float* __restrict__ M2w,
                       const float* __restrict__ M3w) {
  const int bid = blockIdx.x, l = threadIdx.x;
  const float* W; int Ksrc, f;
  if (bid < 144)      { W = O1w; Ksrc = 270; f = bid; }
  else if (bid < 288) { W = M1w; Ksrc = 270; f = bid - 144; }
  else if (bid < 416) { W = O2w; Ksrc = 256; f = bid - 288; }
  else if (bid < 544) { W = M2w; Ksrc = 256; f = bid - 416; }
  else                { W = M3w; Ksrc = 256; f = bid - 544; }
  const int c = f >> 4, nt = f & 15, g = l >> 4, s = l & 15;
  const int of = nt * 16 + s;  // A-operand row (l&15) = of within tile
  union { half8 h; uint4 u; } hv, lv;
#pragma unroll
  for (int i = 0; i < 8; ++i) {
    const int k = c * 32 + g * 8 + i;
    const float w = (k < Ksrc) ? W[k * 256 + of] : 0.f;  // zero-pad K 270..287
    const _Float16 h = (_Float16)w;
    hv.h[i] = h;
    lv.h[i] = (_Float16)((w - (float)h) * SPLIT_S);
  }
  ((uint4*)g_Wh)[bid * 64 + l] = hv.u;
  ((uint4*)g_Wl)[bid * 64 + l] = lv.u;
}

__device__ __forceinline__ half8 as_half8(uint4 u) {
  union { uint4 u4; half8 h; } c; c.u4 = u; return c.h;
}
__device__ __forceinline__ f32x4 mfma16(half8 a, half8 b, f32x4 c) {
  return __builtin_amdgcn_mfma_f32_16x16x32_f16(a, b, c, 0, 0, 0);
}

__device__ __forceinline__ void zero44(f32x4 a1[4][4], f32x4 a2[4][4]) {
#pragma unroll
  for (int n = 0; n < 4; ++n)
#pragma unroll
    for (int sf = 0; sf < 4; ++sf) {
      a1[n][sf] = (f32x4){0.f, 0.f, 0.f, 0.f};
      a2[n][sf] = (f32x4){0.f, 0.f, 0.f, 0.f};
    }
}

// GEMM over CHUNKS K-chunks of 32: wave computes of-tiles {4w..4w+3} for 64
// samples (4 sample-frags). Per c-iter: 8 global dwordx4 (weights, its
// nt-slice only) + 8 ds_read_b128 (B hi/lo) + 48 MFMA. No unpack VALU.
template <int CHUNKS>
__device__ __forceinline__ void lgemm(f32x4 a1[4][4], f32x4 a2[4][4],
                                      const _Float16* __restrict__ Xs,
                                      const uint4* __restrict__ Wh,
                                      const uint4* __restrict__ Wl,
                                      int wu, int g, int s) {
#pragma unroll 1
  for (int c = 0; c < CHUNKS; ++c) {
    uint4 wh[4], wl[4];
#pragma unroll
    for (int n = 0; n < 4; ++n) {
      wh[n] = Wh[(c * 16 + 4 * wu + n) * 64];
      wl[n] = Wl[(c * 16 + 4 * wu + n) * 64];
    }
#pragma unroll
    for (int sf = 0; sf < 4; ++sf) {
      const _Float16* xp = Xs + (16 * sf + s) * RSTR + c * 32 + g * 8;
      half8 bh = *(const half8*)xp;          // hi plane, 16B aligned
      half8 bl = *(const half8*)(xp + 288);  // lo plane
#pragma unroll
      for (int n = 0; n < 4; ++n) {
        a1[n][sf] = mfma16(as_half8(wh[n]), bh, a1[n][sf]);
        a2[n][sf] = mfma16(as_half8(wh[n]), bl, a2[n][sf]);
        a2[n][sf] = mfma16(as_half8(wl[n]), bh, a2[n][sf]);
      }
    }
  }
}

// epilogue -> write relu(acc1 + acc2/2048 + b) split-packed into X planes.
__device__ __forceinline__ void epi_write(const f32x4 a1[4][4], const f32x4 a2[4][4],
                                          const float* __restrict__ bias,  // LDS
                                          _Float16* __restrict__ Xs,
                                          int wu, int g, int s) {
#pragma unroll
  for (int n = 0; n < 4; ++n) {
    const float4 bv = *(const float4*)(bias + (4 * wu + n) * 16 + 4 * g);
    const float bb[4] = {bv.x, bv.y, bv.z, bv.w};
#pragma unroll
    for (int sf = 0; sf < 4; ++sf) {
      union { _Float16 h[4]; uint2 u; } H, L;
#pragma unroll
      for (int r = 0; r < 4; ++r) {
        const float v =
            fmaxf(fmaf(a2[n][sf][r], SPLIT_INV, a1[n][sf][r]) + bb[r], 0.f);
        const _Float16 hh = (_Float16)v;
        H.h[r] = hh;
        L.h[r] = (_Float16)((v - (float)hh) * SPLIT_S);
      }
      _Float16* yp = Xs + (16 * sf + s) * RSTR + (4 * wu + n) * 16 + 4 * g;
      *(uint2*)yp = H.u;
      *(uint2*)(yp + 288) = L.u;
    }
  }
}

// epilogue -> park packed result in registers (M1 while O-branch uses X).
__device__ __forceinline__ void epi_pack(const f32x4 a1[4][4], const f32x4 a2[4][4],
                                         const float* __restrict__ bias,  // LDS
                                         uint2 pkh[4][4], uint2 pkl[4][4],
                                         int wu, int g) {
#pragma unroll
  for (int n = 0; n < 4; ++n) {
    const float4 bv = *(const float4*)(bias + (4 * wu + n) * 16 + 4 * g);
    const float bb[4] = {bv.x, bv.y, bv.z, bv.w};
#pragma unroll
    for (int sf = 0; sf < 4; ++sf) {
      union { _Float16 h[4]; uint2 u; } H, L;
#pragma unroll
      for (int r = 0; r < 4; ++r) {
        const float v =
            fmaxf(fmaf(a2[n][sf][r], SPLIT_INV, a1[n][sf][r]) + bb[r], 0.f);
        const _Float16 hh = (_Float16)v;
        H.h[r] = hh;
        L.h[r] = (_Float16)((v - (float)hh) * SPLIT_S);
      }
      pkh[n][sf] = H.u;
      pkl[n][sf] = L.u;
    }
  }
}

__device__ __forceinline__ void write_pk(const uint2 pkh[4][4], const uint2 pkl[4][4],
                                         _Float16* __restrict__ Xs,
                                         int wu, int g, int s) {
#pragma unroll
  for (int n = 0; n < 4; ++n)
#pragma unroll
    for (int sf = 0; sf < 4; ++sf) {
      _Float16* yp = Xs + (16 * sf + s) * RSTR + (4 * wu + n) * 16 + 4 * g;
      *(uint2*)yp = pkh[n][sf];
      *(uint2*)(yp + 288) = pkl[n][sf];
    }
}

__global__ __launch_bounds__(256, 2) void topdown_mfma(
    const float* __restrict__ towers, const float* __restrict__ aggregate,
    const float* O1b, const float* O2b, const float* O3w,
    const float* O3b, const float* M1b, const float* M2b, const float* M3b,
    float* __restrict__ out) {
  // X: 64 samples x (288 hi | 288 lo | 8 pad) f16 = 74752 B. Row pad doubles
  // as the cross-wave reduction scratch (4 f32/sample). Biases in LDS so the
  // compiler cannot hoist them into registers across the k-loop.
  __shared__ __align__(16) _Float16 Xs[64 * RSTR];
  __shared__ __align__(16) float sb[6 * 256];  // O1b M1b M2b M3b O2b O3w
  const int t = threadIdx.x, l = t & 63;
  const int wu = __builtin_amdgcn_readfirstlane(t >> 6);  // wave id (uniform)
  const int g = l >> 4, s = l & 15;
  const int n0 = blockIdx.x * 64;

  // stage biases (one 256-wide row per plane; blockDim.x == 256)
  sb[0 * 256 + t] = O1b[t];
  sb[1 * 256 + t] = M1b[t];
  sb[2 * 256 + t] = M2b[t];
  sb[3 * 256 + t] = M3b[t];
  sb[4 * 256 + t] = O2b[t];
  sb[5 * 256 + t] = O3w[t];

  // init X: features 0..255 = aggregate (broadcast), 256..287 = 0 (both planes)
  for (int idx = t; idx < 64 * 288; idx += 256) {
    const int ss = idx / 288, f = idx - ss * 288;
    const float v = (f < 256) ? aggregate[f] : 0.f;
    const _Float16 h = (_Float16)v;
    Xs[ss * RSTR + f] = h;
    Xs[ss * RSTR + 288 + f] = (_Float16)((v - (float)h) * SPLIT_S);
  }

  float prod = 1.f;
  const float o3bias = O3b[0];
  f32x4 a1[4][4], a2[4][4];
  uint2 pkh[4][4], pkl[4][4];

  const uint4* WhL = (const uint4*)g_Wh + l;
  const uint4* WlL = (const uint4*)g_Wl + l;

  for (int kk = 0; kk < KS; ++kk) {
    const int tbase = (KS - 1 - kk) * 14;  // reference flips along K
    // tower slice -> features 256..269 (both planes)
    for (int idx = t; idx < 64 * 14; idx += 256) {
      const int ss = idx / 14, f = idx - ss * 14;
      const float v = towers[(size_t)(n0 + ss) * (KS * 14) + tbase + f];
      const _Float16 h = (_Float16)v;
      Xs[ss * RSTR + 256 + f] = h;
      Xs[ss * RSTR + 288 + 256 + f] = (_Float16)((v - (float)h) * SPLIT_S);
    }
    __syncthreads();

    // ---- M1: gemm over X=[A,T]; park result in regs (X still needed by O1)
    zero44(a1, a2);
    lgemm<9>(a1, a2, Xs, WhL + 144 * 64, WlL + 144 * 64, wu, g, s);
    epi_pack(a1, a2, sb + 1 * 256, pkh, pkl, wu, g);

    // ---- O1: gemm over X; then h1 transits through X
    zero44(a1, a2);
    lgemm<9>(a1, a2, Xs, WhL, WlL, wu, g, s);
    __syncthreads();                       // all waves done reading X
    epi_write(a1, a2, sb + 0 * 256, Xs, wu, g, s);  // X[0..255] <- h1
    __syncthreads();                       // h1 visible

    // ---- O2 over h1; fold relu+O3 dot into per-sample partials
    zero44(a1, a2);
    lgemm<8>(a1, a2, Xs, WhL + 288 * 64, WlL + 288 * 64, wu, g, s);
    float tp[4] = {0.f, 0.f, 0.f, 0.f};
#pragma unroll
    for (int n = 0; n < 4; ++n) {
      const int ob = (4 * wu + n) * 16 + 4 * g;
      const float4 bv = *(const float4*)(sb + 4 * 256 + ob);
      const float4 ov = *(const float4*)(sb + 5 * 256 + ob);
      const float bb[4] = {bv.x, bv.y, bv.z, bv.w};
      const float oo[4] = {ov.x, ov.y, ov.z, ov.w};
#pragma unroll
      for (int sf = 0; sf < 4; ++sf)
#pragma unroll
        for (int r = 0; r < 4; ++r)
          tp[sf] +=
              fmaxf(fmaf(a2[n][sf][r], SPLIT_INV, a1[n][sf][r]) + bb[r], 0.f) *
              oo[r];
    }
#pragma unroll
    for (int sf = 0; sf < 4; ++sf) {       // sum over the 4 g-groups
      tp[sf] += __shfl_xor(tp[sf], 16);
      tp[sf] += __shfl_xor(tp[sf], 32);
    }
    if (g == 0) {                          // per-wave partial -> row-pad scratch
#pragma unroll
      for (int sf = 0; sf < 4; ++sf)
        *((float*)(Xs + (16 * sf + s) * RSTR + 576) + wu) = tp[sf];
    }
    __syncthreads();                       // scratch ready; h1 reads done

    // ---- unpark M1 result -> X; update prod
    write_pk(pkh, pkl, Xs, wu, g, s);
    if (t < 64) {
      const float* sp = (const float*)(Xs + t * RSTR + 576);
      const float tt = sp[0] + sp[1] + sp[2] + sp[3] + o3bias;
      prod *= 1.f / (1.f + expf(-tt));
    }
    __syncthreads();                       // A' visible

    // ---- M2 (in place with read/write barriers)
    zero44(a1, a2);
    lgemm<8>(a1, a2, Xs, WhL + 416 * 64, WlL + 416 * 64, wu, g, s);
    __syncthreads();
    epi_write(a1, a2, sb + 2 * 256, Xs, wu, g, s);
    __syncthreads();

    // ---- M3
    zero44(a1, a2);
    lgemm<8>(a1, a2, Xs, WhL + 544 * 64, WlL + 544 * 64, wu, g, s);
    __syncthreads();
    epi_write(a1, a2, sb + 3 * 256, Xs, wu, g, s);
    __syncthreads();
  }

  if (t < 64) out[n0 + t] = prod;
}

extern "C" void kernel_launch(void* const* d_in, const int* in_sizes, int n_in,
                              void* d_out, int out_size, void* d_ws, size_t ws_size,
                              hipStream_t stream) {
  const float* towers    = (const float*)d_in[0];
  const float* aggregate = (const float*)d_in[1];
  const float* M1w = (const float*)d_in[2];
  const float* M1b = (const float*)d_in[3];
  const float* M2w = (const float*)d_in[4];
  const float* M2b = (const float*)d_in[5];
  const float* M3w = (const float*)d_in[6];
  const float* M3b = (const float*)d_in[7];
  const float* O1w = (const float*)d_in[8];
  const float* O1b = (const float*)d_in[9];
  const float* O2w = (const float*)d_in[10];
  const float* O2b = (const float*)d_in[11];
  const float* O3w = (const float*)d_in[12];
  const float* O3b = (const float*)d_in[13];
  float* out = (float*)d_out;

  prep_w<<<672, 64, 0, stream>>>(O1w, M1w, O2w, M2w, M3w);

  const int nblocks = out_size / 64;  // 2048 blocks x 256 threads (4 waves)
  topdown_mfma<<<nblocks, 256, 0, stream>>>(towers, aggregate, O1b, O2b, O3w,
                                            O3b, M1b, M2b, M3b, out);
}

// Round 4
// 2631.094 us; speedup vs baseline: 8.7342x; 1.1916x over previous
//
#include <hip/hip_runtime.h>
#include <math.h>
#include <stdint.h>

// ============================================================================
// TopDownNet via split-f16 MFMA, R8 = R7 with the cvt_pkrtz type fix.
// R6 (3135 us): MfmaUtil 37% = MFMA floor; rest lost to (a) register spills
// (WRITE_SIZE 1.46 GB at the 256-reg cap: acc128+park64+weights+temps),
// (b) LDS bank conflicts 1.5e8 (s vs s+8 same bank-quad on every b128/b64),
// (c) epilogue pack VALU. This revision:
//  - M1 "park" moved from 64 VGPRs to a static __device__ buffer (wave-private
//    coalesced 16KB slot; stores drain at the next barrier, loads hide under
//    the O3 tail) -> peak ~190 regs, no spills.
//  - X swizzle: physical f16 index = logical ^ (s&8) (row-bit3 XOR) applied to
//    ALL X accesses -> s/s+8 bank-quad collision removed.
//  - biases read from global (L1), scratch in its own 1KB LDS array; row pad
//    stays permanently zero (safe: i<576 => i^8 < 576).
//  - split-pack via v_cvt_pkrtz_f16_f32 (native __fp16x2 return type).
// Split math (validated R5/R6, absmax 3.8e-6): x = xh + xl*2^-11, w likewise;
//   acc1 += xh*wh ; acc2 += xh*wl + xl*wh ; result = acc1 + acc2/2048.
// Fragment layouts (gfx950 16x16x32): A row=l&15 (of), k=(l>>4)*8+i;
//   B col=l&15 (sample), same k; D row=(l>>4)*4+r, col=l&15.
// ============================================================================

typedef _Float16 half8 __attribute__((ext_vector_type(8)));
typedef __fp16 fp16x2 __attribute__((ext_vector_type(2)));  // cvt_pkrtz native
typedef float f32x4 __attribute__((ext_vector_type(4)));

constexpr int KS = 10;
constexpr int RSTR = 584;  // f16/row: 288 hi + 288 lo + 8 pad (pad stays ZERO)
constexpr float SPLIT_S = 2048.f;
constexpr float SPLIT_INV = 1.f / 2048.f;

// W^T fragment streams (verified in R5/R6). Frag idx: O1 0-143, M1 144-287,
// O2 288-415, M2 416-543, M3 544-671. Frag = 64 lanes x 8 f16.
__device__ __align__(16) _Float16 g_Wh[672 * 512];
__device__ __align__(16) _Float16 g_Wl[672 * 512];
// M1 park: 2048 blocks x 4 waves x 16 uint4 x 64 lanes = 128 MB.
__device__ __align__(16) uint4 g_park[2048u * 4u * 16u * 64u];

__global__ void prep_w(const float* __restrict__ O1w, const float* __restrict__ M1w,
                       const float* __restrict__ O2w, const float* __restrict__ M2w,
                       const float* __restrict__ M3w) {
  const int bid = blockIdx.x, l = threadIdx.x;
  const float* W; int Ksrc, f;
  if (bid < 144)      { W = O1w; Ksrc = 270; f = bid; }
  else if (bid < 288) { W = M1w; Ksrc = 270; f = bid - 144; }
  else if (bid < 416) { W = O2w; Ksrc = 256; f = bid - 288; }
  else if (bid < 544) { W = M2w; Ksrc = 256; f = bid - 416; }
  else                { W = M3w; Ksrc = 256; f = bid - 544; }
  const int c = f >> 4, nt = f & 15, g = l >> 4, s = l & 15;
  const int of = nt * 16 + s;
  union { half8 h; uint4 u; } hv, lv;
#pragma unroll
  for (int i = 0; i < 8; ++i) {
    const int k = c * 32 + g * 8 + i;
    const float w = (k < Ksrc) ? W[k * 256 + of] : 0.f;  // zero-pad K 270..287
    const _Float16 h = (_Float16)w;
    hv.h[i] = h;
    lv.h[i] = (_Float16)((w - (float)h) * SPLIT_S);
  }
  ((uint4*)g_Wh)[bid * 64 + l] = hv.u;
  ((uint4*)g_Wl)[bid * 64 + l] = lv.u;
}

__device__ __forceinline__ half8 as_half8(uint4 u) {
  union { uint4 u4; half8 h; } c; c.u4 = u; return c.h;
}
__device__ __forceinline__ f32x4 mfma16(half8 a, half8 b, f32x4 c) {
  return __builtin_amdgcn_mfma_f32_16x16x32_f16(a, b, c, 0, 0, 0);
}
__device__ __forceinline__ uint32_t h2bits(fp16x2 h) {
  union { fp16x2 h2; uint32_t u; } c; c.h2 = h; return c.u;
}

struct PK { uint2 hi, lo; };
// RTZ split-pack of 4 f32 -> 4 f16-hi + 4 f16-lo (residual * 2048).
__device__ __forceinline__ PK split4(float v0, float v1, float v2, float v3) {
  fp16x2 h01 = __builtin_amdgcn_cvt_pkrtz(v0, v1);
  fp16x2 h23 = __builtin_amdgcn_cvt_pkrtz(v2, v3);
  fp16x2 l01 = __builtin_amdgcn_cvt_pkrtz((v0 - (float)h01[0]) * SPLIT_S,
                                          (v1 - (float)h01[1]) * SPLIT_S);
  fp16x2 l23 = __builtin_amdgcn_cvt_pkrtz((v2 - (float)h23[0]) * SPLIT_S,
                                          (v3 - (float)h23[1]) * SPLIT_S);
  PK r;
  r.hi = make_uint2(h2bits(h01), h2bits(h23));
  r.lo = make_uint2(h2bits(l01), h2bits(l23));
  return r;
}
__device__ __forceinline__ void split1(float v, _Float16& h, _Float16& l) {
  h = (_Float16)v;
  l = (_Float16)((v - (float)h) * SPLIT_S);
}

// Physical f16 index for logical feature i of row (xr = row&8 = s&8).
__device__ __forceinline__ int xidx(int row, int i, int xr) {
  return row * RSTR + (i ^ xr);
}

__device__ __forceinline__ void zero44(f32x4 a1[4][4], f32x4 a2[4][4]) {
#pragma unroll
  for (int n = 0; n < 4; ++n)
#pragma unroll
    for (int sf = 0; sf < 4; ++sf) {
      a1[n][sf] = (f32x4){0.f, 0.f, 0.f, 0.f};
      a2[n][sf] = (f32x4){0.f, 0.f, 0.f, 0.f};
    }
}

// GEMM over CHUNKS K-chunks of 32: wave computes of-tiles {4wu..4wu+3} for 64
// samples. Per c: 8 global dwordx4 (weights) + 8 ds_read_b128 (B hi/lo, XOR-
// swizzled) + 48 MFMA.
template <int CHUNKS>
__device__ __forceinline__ void lgemm(f32x4 a1[4][4], f32x4 a2[4][4],
                                      const _Float16* __restrict__ Xs,
                                      const uint4* __restrict__ Wh,
                                      const uint4* __restrict__ Wl,
                                      int wu, int g, int s, int xr) {
#pragma unroll 1
  for (int c = 0; c < CHUNKS; ++c) {
    uint4 wh[4], wl[4];
#pragma unroll
    for (int n = 0; n < 4; ++n) {
      wh[n] = Wh[(c * 16 + 4 * wu + n) * 64];
      wl[n] = Wl[(c * 16 + 4 * wu + n) * 64];
    }
#pragma unroll
    for (int sf = 0; sf < 4; ++sf) {
      const _Float16* xp = Xs + xidx(16 * sf + s, c * 32 + g * 8, xr);
      half8 bh = *(const half8*)xp;          // hi plane (16B aligned)
      half8 bl = *(const half8*)(xp + 288);  // lo plane
#pragma unroll
      for (int n = 0; n < 4; ++n) {
        a1[n][sf] = mfma16(as_half8(wh[n]), bh, a1[n][sf]);
        a2[n][sf] = mfma16(as_half8(wh[n]), bl, a2[n][sf]);
        a2[n][sf] = mfma16(as_half8(wl[n]), bh, a2[n][sf]);
      }
    }
  }
}

// relu(acc1 + acc2/2048 + bias) split-packed into X planes (swizzled).
__device__ __forceinline__ void epi_write(const f32x4 a1[4][4], const f32x4 a2[4][4],
                                          const float* __restrict__ bias,  // global
                                          _Float16* __restrict__ Xs,
                                          int wu, int g, int s, int xr) {
#pragma unroll
  for (int n = 0; n < 4; ++n) {
    const float4 bv = *(const float4*)(bias + (4 * wu + n) * 16 + 4 * g);
#pragma unroll
    for (int sf = 0; sf < 4; ++sf) {
      const float v0 = fmaxf(fmaf(a2[n][sf][0], SPLIT_INV, a1[n][sf][0]) + bv.x, 0.f);
      const float v1 = fmaxf(fmaf(a2[n][sf][1], SPLIT_INV, a1[n][sf][1]) + bv.y, 0.f);
      const float v2 = fmaxf(fmaf(a2[n][sf][2], SPLIT_INV, a1[n][sf][2]) + bv.z, 0.f);
      const float v3 = fmaxf(fmaf(a2[n][sf][3], SPLIT_INV, a1[n][sf][3]) + bv.w, 0.f);
      const PK p = split4(v0, v1, v2, v3);
      _Float16* yp = Xs + xidx(16 * sf + s, (4 * wu + n) * 16 + 4 * g, xr);
      *(uint2*)yp = p.hi;
      *(uint2*)(yp + 288) = p.lo;
    }
  }
}

// M1 epilogue -> coalesced park in global (wave-private slot).
__device__ __forceinline__ void epi_park(const f32x4 a1[4][4], const f32x4 a2[4][4],
                                         const float* __restrict__ bias,
                                         uint4* __restrict__ slot,
                                         int wu, int g, int l) {
#pragma unroll
  for (int n = 0; n < 4; ++n) {
    const float4 bv = *(const float4*)(bias + (4 * wu + n) * 16 + 4 * g);
#pragma unroll
    for (int p = 0; p < 2; ++p) {
      PK q[2];
#pragma unroll
      for (int h = 0; h < 2; ++h) {
        const int sf = 2 * p + h;
        const float v0 = fmaxf(fmaf(a2[n][sf][0], SPLIT_INV, a1[n][sf][0]) + bv.x, 0.f);
        const float v1 = fmaxf(fmaf(a2[n][sf][1], SPLIT_INV, a1[n][sf][1]) + bv.y, 0.f);
        const float v2 = fmaxf(fmaf(a2[n][sf][2], SPLIT_INV, a1[n][sf][2]) + bv.z, 0.f);
        const float v3 = fmaxf(fmaf(a2[n][sf][3], SPLIT_INV, a1[n][sf][3]) + bv.w, 0.f);
        q[h] = split4(v0, v1, v2, v3);
      }
      slot[(n * 2 + p) * 64 + l]     = make_uint4(q[0].hi.x, q[0].hi.y, q[1].hi.x, q[1].hi.y);
      slot[(8 + n * 2 + p) * 64 + l] = make_uint4(q[0].lo.x, q[0].lo.y, q[1].lo.x, q[1].lo.y);
    }
  }
}

// unpark loaded uint4s -> X planes (swizzled).
__device__ __forceinline__ void unpark_write(const uint4 pk[16],
                                             _Float16* __restrict__ Xs,
                                             int wu, int g, int s, int xr) {
#pragma unroll
  for (int n = 0; n < 4; ++n)
#pragma unroll
    for (int p = 0; p < 2; ++p) {
      const uint4 hi = pk[n * 2 + p];
      const uint4 lo = pk[8 + n * 2 + p];
#pragma unroll
      for (int h = 0; h < 2; ++h) {
        const int sf = 2 * p + h;
        _Float16* yp = Xs + xidx(16 * sf + s, (4 * wu + n) * 16 + 4 * g, xr);
        *(uint2*)yp = h ? make_uint2(hi.z, hi.w) : make_uint2(hi.x, hi.y);
        *(uint2*)(yp + 288) = h ? make_uint2(lo.z, lo.w) : make_uint2(lo.x, lo.y);
      }
    }
}

__global__ __launch_bounds__(256, 2) void topdown_mfma(
    const float* __restrict__ towers, const float* __restrict__ aggregate,
    const float* __restrict__ O1b, const float* __restrict__ O2b,
    const float* __restrict__ O3w, const float* __restrict__ O3b,
    const float* __restrict__ M1b, const float* __restrict__ M2b,
    const float* __restrict__ M3b, float* __restrict__ out) {
  __shared__ __align__(16) _Float16 Xs[64 * RSTR];  // 74752 B
  __shared__ __align__(16) float scr[64][4];        // 1 KB cross-wave reduce
  const int t = threadIdx.x, l = t & 63;
  const int wu = __builtin_amdgcn_readfirstlane(t >> 6);
  const int g = l >> 4, s = l & 15;
  const int xr = s & 8;  // row-bit3 == s-bit3 for all rows this lane touches
  const int n0 = blockIdx.x * 64;
  uint4* park = g_park + ((size_t)blockIdx.x * 4 + (size_t)wu) * (16 * 64);

  // init X: logical features 0..255 = aggregate, 256..287 = 0 (both planes).
  // Row pad (f16 idx 576..583) is never written -> stays 0.
  for (int idx = t; idx < 64 * 288; idx += 256) {
    const int ss = idx / 288, f = idx - ss * 288;
    const float v = (f < 256) ? aggregate[f] : 0.f;
    _Float16 h, lo; split1(v, h, lo);
    const int p = xidx(ss, f, ss & 8);
    Xs[p] = h;
    Xs[p + 288] = lo;
  }

  float prod = 1.f;
  const float o3bias = O3b[0];
  f32x4 a1[4][4], a2[4][4];

  const uint4* WhL = (const uint4*)g_Wh + l;
  const uint4* WlL = (const uint4*)g_Wl + l;

  for (int kk = 0; kk < KS; ++kk) {
    const int tbase = (KS - 1 - kk) * 14;  // reference flips along K
    // tower slice -> logical features 256..269 (both planes)
    for (int idx = t; idx < 64 * 14; idx += 256) {
      const int ss = idx / 14, f = idx - ss * 14;
      const float v = towers[(size_t)(n0 + ss) * (KS * 14) + tbase + f];
      _Float16 h, lo; split1(v, h, lo);
      const int p = xidx(ss, 256 + f, ss & 8);
      Xs[p] = h;
      Xs[p + 288] = lo;
    }
    __syncthreads();  // (a) towers + previous A' visible

    // ---- M1 over X=[A,T]; result -> global park (frees 64 regs vs R6)
    zero44(a1, a2);
    lgemm<9>(a1, a2, Xs, WhL + 144 * 64, WlL + 144 * 64, wu, g, s, xr);
    epi_park(a1, a2, M1b, park, wu, g, l);

    // ---- O1 over X
    zero44(a1, a2);
    lgemm<9>(a1, a2, Xs, WhL, WlL, wu, g, s, xr);
    __syncthreads();  // (b) all X reads done; park stores drained
    epi_write(a1, a2, O1b, Xs, wu, g, s, xr);  // X[0..255] <- h1
    __syncthreads();  // (c) h1 visible

    // ---- O2 over h1
    zero44(a1, a2);
    lgemm<8>(a1, a2, Xs, WhL + 288 * 64, WlL + 288 * 64, wu, g, s, xr);

    // unpark loads issued now; latency hides under the O3 tail + barrier
    asm volatile("" ::: "memory");
    uint4 pk[16];
#pragma unroll
    for (int q = 0; q < 16; ++q) pk[q] = park[q * 64 + l];

    // O3 tail: relu(O2) dot O3w -> per-sample partials
    float tp[4] = {0.f, 0.f, 0.f, 0.f};
#pragma unroll
    for (int n = 0; n < 4; ++n) {
      const int ob = (4 * wu + n) * 16 + 4 * g;
      const float4 bv = *(const float4*)(O2b + ob);
      const float4 ov = *(const float4*)(O3w + ob);
      const float bb[4] = {bv.x, bv.y, bv.z, bv.w};
      const float oo[4] = {ov.x, ov.y, ov.z, ov.w};
#pragma unroll
      for (int sf = 0; sf < 4; ++sf)
#pragma unroll
        for (int r = 0; r < 4; ++r)
          tp[sf] += fmaxf(fmaf(a2[n][sf][r], SPLIT_INV, a1[n][sf][r]) + bb[r], 0.f) * oo[r];
    }
#pragma unroll
    for (int sf = 0; sf < 4; ++sf) {
      tp[sf] += __shfl_xor(tp[sf], 16);
      tp[sf] += __shfl_xor(tp[sf], 32);
    }
    if (g == 0) {
#pragma unroll
      for (int sf = 0; sf < 4; ++sf) scr[16 * sf + s][wu] = tp[sf];
    }
    __syncthreads();  // (d) scr ready; all h1 reads done

    unpark_write(pk, Xs, wu, g, s, xr);  // X <- A' (M1 result)
    if (t < 64) {
      const float4 sv = *(const float4*)(scr[t]);
      prod *= 1.f / (1.f + expf(-(sv.x + sv.y + sv.z + sv.w + o3bias)));
    }
    __syncthreads();  // (e) A' visible

    // ---- M2 (in place)
    zero44(a1, a2);
    lgemm<8>(a1, a2, Xs, WhL + 416 * 64, WlL + 416 * 64, wu, g, s, xr);
    __syncthreads();  // (f) reads done
    epi_write(a1, a2, M2b, Xs, wu, g, s, xr);
    __syncthreads();  // (g)

    // ---- M3 (in place); next-iter sync (a) covers the write->read edge
    zero44(a1, a2);
    lgemm<8>(a1, a2, Xs, WhL + 544 * 64, WlL + 544 * 64, wu, g, s, xr);
    __syncthreads();  // (h) reads done
    epi_write(a1, a2, M3b, Xs, wu, g, s, xr);
  }

  if (t < 64) out[n0 + t] = prod;
}

extern "C" void kernel_launch(void* const* d_in, const int* in_sizes, int n_in,
                              void* d_out, int out_size, void* d_ws, size_t ws_size,
                              hipStream_t stream) {
  const float* towers    = (const float*)d_in[0];
  const float* aggregate = (const float*)d_in[1];
  const float* M1w = (const float*)d_in[2];
  const float* M1b = (const float*)d_in[3];
  const float* M2w = (const float*)d_in[4];
  const float* M2b = (const float*)d_in[5];
  const float* M3w = (const float*)d_in[6];
  const float* M3b = (const float*)d_in[7];
  const float* O1w = (const float*)d_in[8];
  const float* O1b = (const float*)d_in[9];
  const float* O2w = (const float*)d_in[10];
  const float* O2b = (const float*)d_in[11];
  const float* O3w = (const float*)d_in[12];
  const float* O3b = (const float*)d_in[13];
  float* out = (float*)d_out;

  prep_w<<<672, 64, 0, stream>>>(O1w, M1w, O2w, M2w, M3w);

  const int nblocks = out_size / 64;  // 2048 blocks x 256 threads (4 waves)
  topdown_mfma<<<nblocks, 256, 0, stream>>>(towers, aggregate, O1b, O2b, O3w,
                                            O3b, M1b, M2b, M3b, out);
}

// Round 5
// 2407.703 us; speedup vs baseline: 9.5445x; 1.0928x over previous
//
#include <hip/hip_runtime.h>
#include <math.h>
#include <stdint.h>

// ============================================================================
// TopDownNet via split-f16 MFMA, R9: occupancy doubling.
// R8 (2631 us): MfmaUtil 46.6% == MFMA-demand/time -> stall-limited at
// 2 waves/SIMD (VGPR 128 + acc 128 = 256/wave cap). R9: 64-sample block with
// 8 waves, of-EIGHTH split per wave (2 nt-tiles x 4 sample-frags):
//  - acc 128 -> 64 regs; __launch_bounds__(512,4) caps 128 regs/wave
//    -> 16 waves/CU = 4 waves/SIMD (double R8).
//  - weight demand unchanged (~27.5 GB: waves 2x, per-wave loads 0.5x).
//  - LDS unchanged 76.8 KB -> 2 blocks/CU.
//  - R8's XOR swizzle removed: proven no-op (conflict counter bit-identical
//    R6 vs R8; row stride 292 dwords = 4 mod 32 makes s/s+8 alias regardless;
//    8 lanes/bank-quad is structural for wave64 b128). Saves address VALU.
// Split math (validated R5-R8, absmax 3.8e-6): x = xh + xl*2^-11, w likewise;
//   acc1 += xh*wh ; acc2 += xh*wl + xl*wh ; result = acc1 + acc2/2048.
// Fragment layouts (gfx950 16x16x32): A row=l&15 (of), k=(l>>4)*8+i;
//   B col=l&15 (sample), same k; D row=(l>>4)*4+r, col=l&15.
// ============================================================================

typedef _Float16 half8 __attribute__((ext_vector_type(8)));
typedef __fp16 fp16x2 __attribute__((ext_vector_type(2)));  // cvt_pkrtz native
typedef float f32x4 __attribute__((ext_vector_type(4)));

constexpr int KS = 10;
constexpr int RSTR = 584;  // f16/row: 288 hi + 288 lo + 8 pad
constexpr float SPLIT_S = 2048.f;
constexpr float SPLIT_INV = 1.f / 2048.f;

// W^T fragment streams (layout unchanged since R5; wave-decomposition-agnostic).
// Frag idx: O1 0-143, M1 144-287, O2 288-415, M2 416-543, M3 544-671.
__device__ __align__(16) _Float16 g_Wh[672 * 512];
__device__ __align__(16) _Float16 g_Wl[672 * 512];
// M1 park: 2048 blocks x 8 waves x 8 uint4 x 64 lanes = 134 MB (wave-private).
__device__ __align__(16) uint4 g_park[2048u * 8u * 8u * 64u];

__global__ void prep_w(const float* __restrict__ O1w, const float* __restrict__ M1w,
                       const float* __restrict__ O2w, const float* __restrict__ M2w,
                       const float* __restrict__ M3w) {
  const int bid = blockIdx.x, l = threadIdx.x;
  const float* W; int Ksrc, f;
  if (bid < 144)      { W = O1w; Ksrc = 270; f = bid; }
  else if (bid < 288) { W = M1w; Ksrc = 270; f = bid - 144; }
  else if (bid < 416) { W = O2w; Ksrc = 256; f = bid - 288; }
  else if (bid < 544) { W = M2w; Ksrc = 256; f = bid - 416; }
  else                { W = M3w; Ksrc = 256; f = bid - 544; }
  const int c = f >> 4, nt = f & 15, g = l >> 4, s = l & 15;
  const int of = nt * 16 + s;
  union { half8 h; uint4 u; } hv, lv;
#pragma unroll
  for (int i = 0; i < 8; ++i) {
    const int k = c * 32 + g * 8 + i;
    const float w = (k < Ksrc) ? W[k * 256 + of] : 0.f;  // zero-pad K 270..287
    const _Float16 h = (_Float16)w;
    hv.h[i] = h;
    lv.h[i] = (_Float16)((w - (float)h) * SPLIT_S);
  }
  ((uint4*)g_Wh)[bid * 64 + l] = hv.u;
  ((uint4*)g_Wl)[bid * 64 + l] = lv.u;
}

__device__ __forceinline__ half8 as_half8(uint4 u) {
  union { uint4 u4; half8 h; } c; c.u4 = u; return c.h;
}
__device__ __forceinline__ f32x4 mfma16(half8 a, half8 b, f32x4 c) {
  return __builtin_amdgcn_mfma_f32_16x16x32_f16(a, b, c, 0, 0, 0);
}
__device__ __forceinline__ uint32_t h2bits(fp16x2 h) {
  union { fp16x2 h2; uint32_t u; } c; c.h2 = h; return c.u;
}

struct PK { uint2 hi, lo; };
// RTZ split-pack of 4 f32 -> 4 f16-hi + 4 f16-lo (residual * 2048).
__device__ __forceinline__ PK split4(float v0, float v1, float v2, float v3) {
  fp16x2 h01 = __builtin_amdgcn_cvt_pkrtz(v0, v1);
  fp16x2 h23 = __builtin_amdgcn_cvt_pkrtz(v2, v3);
  fp16x2 l01 = __builtin_amdgcn_cvt_pkrtz((v0 - (float)h01[0]) * SPLIT_S,
                                          (v1 - (float)h01[1]) * SPLIT_S);
  fp16x2 l23 = __builtin_amdgcn_cvt_pkrtz((v2 - (float)h23[0]) * SPLIT_S,
                                          (v3 - (float)h23[1]) * SPLIT_S);
  PK r;
  r.hi = make_uint2(h2bits(h01), h2bits(h23));
  r.lo = make_uint2(h2bits(l01), h2bits(l23));
  return r;
}
__device__ __forceinline__ void split1(float v, _Float16& h, _Float16& l) {
  h = (_Float16)v;
  l = (_Float16)((v - (float)h) * SPLIT_S);
}

__device__ __forceinline__ void zero24(f32x4 a1[2][4], f32x4 a2[2][4]) {
#pragma unroll
  for (int n = 0; n < 2; ++n)
#pragma unroll
    for (int sf = 0; sf < 4; ++sf) {
      a1[n][sf] = (f32x4){0.f, 0.f, 0.f, 0.f};
      a2[n][sf] = (f32x4){0.f, 0.f, 0.f, 0.f};
    }
}

// GEMM over CHUNKS K-chunks of 32: wave computes of-tiles {2wu, 2wu+1} for 64
// samples. Per c: 4 global dwordx4 (weights, reused over 4 sf) +
// 8 ds_read_b128 (B hi/lo) + 24 MFMA.
template <int CHUNKS>
__device__ __forceinline__ void lgemm(f32x4 a1[2][4], f32x4 a2[2][4],
                                      const _Float16* __restrict__ Xs,
                                      const uint4* __restrict__ Wh,
                                      const uint4* __restrict__ Wl,
                                      int wu, int g, int s) {
#pragma unroll 1
  for (int c = 0; c < CHUNKS; ++c) {
    uint4 wh[2], wl[2];
#pragma unroll
    for (int n = 0; n < 2; ++n) {
      wh[n] = Wh[(c * 16 + 2 * wu + n) * 64];
      wl[n] = Wl[(c * 16 + 2 * wu + n) * 64];
    }
#pragma unroll
    for (int sf = 0; sf < 4; ++sf) {
      const _Float16* xp = Xs + (16 * sf + s) * RSTR + c * 32 + g * 8;
      half8 bh = *(const half8*)xp;          // hi plane (16B aligned)
      half8 bl = *(const half8*)(xp + 288);  // lo plane
#pragma unroll
      for (int n = 0; n < 2; ++n) {
        a1[n][sf] = mfma16(as_half8(wh[n]), bh, a1[n][sf]);
        a2[n][sf] = mfma16(as_half8(wh[n]), bl, a2[n][sf]);
        a2[n][sf] = mfma16(as_half8(wl[n]), bh, a2[n][sf]);
      }
    }
  }
}

// relu(acc1 + acc2/2048 + bias) split-packed into X planes.
__device__ __forceinline__ void epi_write(const f32x4 a1[2][4], const f32x4 a2[2][4],
                                          const float* __restrict__ bias,  // global
                                          _Float16* __restrict__ Xs,
                                          int wu, int g, int s) {
#pragma unroll
  for (int n = 0; n < 2; ++n) {
    const float4 bv = *(const float4*)(bias + (2 * wu + n) * 16 + 4 * g);
#pragma unroll
    for (int sf = 0; sf < 4; ++sf) {
      const float v0 = fmaxf(fmaf(a2[n][sf][0], SPLIT_INV, a1[n][sf][0]) + bv.x, 0.f);
      const float v1 = fmaxf(fmaf(a2[n][sf][1], SPLIT_INV, a1[n][sf][1]) + bv.y, 0.f);
      const float v2 = fmaxf(fmaf(a2[n][sf][2], SPLIT_INV, a1[n][sf][2]) + bv.z, 0.f);
      const float v3 = fmaxf(fmaf(a2[n][sf][3], SPLIT_INV, a1[n][sf][3]) + bv.w, 0.f);
      const PK p = split4(v0, v1, v2, v3);
      _Float16* yp = Xs + (16 * sf + s) * RSTR + (2 * wu + n) * 16 + 4 * g;
      *(uint2*)yp = p.hi;
      *(uint2*)(yp + 288) = p.lo;
    }
  }
}

// M1 epilogue -> coalesced park in global (wave-private slot, 8 uint4/lane).
__device__ __forceinline__ void epi_park(const f32x4 a1[2][4], const f32x4 a2[2][4],
                                         const float* __restrict__ bias,
                                         uint4* __restrict__ slot,
                                         int wu, int g, int l) {
#pragma unroll
  for (int n = 0; n < 2; ++n) {
    const float4 bv = *(const float4*)(bias + (2 * wu + n) * 16 + 4 * g);
#pragma unroll
    for (int p = 0; p < 2; ++p) {
      PK q[2];
#pragma unroll
      for (int h = 0; h < 2; ++h) {
        const int sf = 2 * p + h;
        const float v0 = fmaxf(fmaf(a2[n][sf][0], SPLIT_INV, a1[n][sf][0]) + bv.x, 0.f);
        const float v1 = fmaxf(fmaf(a2[n][sf][1], SPLIT_INV, a1[n][sf][1]) + bv.y, 0.f);
        const float v2 = fmaxf(fmaf(a2[n][sf][2], SPLIT_INV, a1[n][sf][2]) + bv.z, 0.f);
        const float v3 = fmaxf(fmaf(a2[n][sf][3], SPLIT_INV, a1[n][sf][3]) + bv.w, 0.f);
        q[h] = split4(v0, v1, v2, v3);
      }
      slot[(n * 2 + p) * 64 + l]     = make_uint4(q[0].hi.x, q[0].hi.y, q[1].hi.x, q[1].hi.y);
      slot[(4 + n * 2 + p) * 64 + l] = make_uint4(q[0].lo.x, q[0].lo.y, q[1].lo.x, q[1].lo.y);
    }
  }
}

// unpark loaded uint4s -> X planes.
__device__ __forceinline__ void unpark_write(const uint4 pk[8],
                                             _Float16* __restrict__ Xs,
                                             int wu, int g, int s) {
#pragma unroll
  for (int n = 0; n < 2; ++n)
#pragma unroll
    for (int p = 0; p < 2; ++p) {
      const uint4 hi = pk[n * 2 + p];
      const uint4 lo = pk[4 + n * 2 + p];
#pragma unroll
      for (int h = 0; h < 2; ++h) {
        const int sf = 2 * p + h;
        _Float16* yp = Xs + (16 * sf + s) * RSTR + (2 * wu + n) * 16 + 4 * g;
        *(uint2*)yp = h ? make_uint2(hi.z, hi.w) : make_uint2(hi.x, hi.y);
        *(uint2*)(yp + 288) = h ? make_uint2(lo.z, lo.w) : make_uint2(lo.x, lo.y);
      }
    }
}

__global__ __launch_bounds__(512, 4) void topdown_mfma(
    const float* __restrict__ towers, const float* __restrict__ aggregate,
    const float* __restrict__ O1b, const float* __restrict__ O2b,
    const float* __restrict__ O3w, const float* __restrict__ O3b,
    const float* __restrict__ M1b, const float* __restrict__ M2b,
    const float* __restrict__ M3b, float* __restrict__ out) {
  __shared__ __align__(16) _Float16 Xs[64 * RSTR];  // 74752 B
  __shared__ __align__(16) float scr[64][8];        // 2 KB cross-wave reduce
  const int t = threadIdx.x, l = t & 63;
  const int wu = __builtin_amdgcn_readfirstlane(t >> 6);  // wave id 0..7
  const int g = l >> 4, s = l & 15;
  const int n0 = blockIdx.x * 64;
  uint4* park = g_park + ((size_t)blockIdx.x * 8 + (size_t)wu) * (8 * 64);

  // init X: logical features 0..255 = aggregate, 256..287 = 0 (both planes).
  for (int idx = t; idx < 64 * 288; idx += 512) {
    const int ss = idx / 288, f = idx - ss * 288;
    const float v = (f < 256) ? aggregate[f] : 0.f;
    _Float16 h, lo; split1(v, h, lo);
    Xs[ss * RSTR + f] = h;
    Xs[ss * RSTR + 288 + f] = lo;
  }

  float prod = 1.f;
  const float o3bias = O3b[0];
  f32x4 a1[2][4], a2[2][4];

  const uint4* WhL = (const uint4*)g_Wh + l;
  const uint4* WlL = (const uint4*)g_Wl + l;

  for (int kk = 0; kk < KS; ++kk) {
    const int tbase = (KS - 1 - kk) * 14;  // reference flips along K
    // tower slice -> logical features 256..269 (both planes)
    for (int idx = t; idx < 64 * 14; idx += 512) {
      const int ss = idx / 14, f = idx - ss * 14;
      const float v = towers[(size_t)(n0 + ss) * (KS * 14) + tbase + f];
      _Float16 h, lo; split1(v, h, lo);
      Xs[ss * RSTR + 256 + f] = h;
      Xs[ss * RSTR + 288 + 256 + f] = lo;
    }
    __syncthreads();  // (a) towers + previous A' visible

    // ---- M1 over X=[A,T]; result -> global park
    zero24(a1, a2);
    lgemm<9>(a1, a2, Xs, WhL + 144 * 64, WlL + 144 * 64, wu, g, s);
    epi_park(a1, a2, M1b, park, wu, g, l);

    // ---- O1 over X
    zero24(a1, a2);
    lgemm<9>(a1, a2, Xs, WhL, WlL, wu, g, s);
    __syncthreads();  // (b) all X reads done
    epi_write(a1, a2, O1b, Xs, wu, g, s);  // X[0..255] <- h1
    __syncthreads();  // (c) h1 visible

    // ---- O2 over h1
    zero24(a1, a2);
    lgemm<8>(a1, a2, Xs, WhL + 288 * 64, WlL + 288 * 64, wu, g, s);

    // unpark loads issued now (wave-private; latency hides under O3 tail)
    asm volatile("" ::: "memory");
    uint4 pk[8];
#pragma unroll
    for (int q = 0; q < 8; ++q) pk[q] = park[q * 64 + l];

    // O3 tail: relu(O2) dot O3w -> per-sample partials
    float tp[4] = {0.f, 0.f, 0.f, 0.f};
#pragma unroll
    for (int n = 0; n < 2; ++n) {
      const int ob = (2 * wu + n) * 16 + 4 * g;
      const float4 bv = *(const float4*)(O2b + ob);
      const float4 ov = *(const float4*)(O3w + ob);
      const float bb[4] = {bv.x, bv.y, bv.z, bv.w};
      const float oo[4] = {ov.x, ov.y, ov.z, ov.w};
#pragma unroll
      for (int sf = 0; sf < 4; ++sf)
#pragma unroll
        for (int r = 0; r < 4; ++r)
          tp[sf] += fmaxf(fmaf(a2[n][sf][r], SPLIT_INV, a1[n][sf][r]) + bb[r], 0.f) * oo[r];
    }
#pragma unroll
    for (int sf = 0; sf < 4; ++sf) {
      tp[sf] += __shfl_xor(tp[sf], 16);
      tp[sf] += __shfl_xor(tp[sf], 32);
    }
    if (g == 0) {
#pragma unroll
      for (int sf = 0; sf < 4; ++sf) scr[16 * sf + s][wu] = tp[sf];
    }
    __syncthreads();  // (d) scr ready; all h1 reads done

    unpark_write(pk, Xs, wu, g, s);  // X <- A' (M1 result)
    if (t < 64) {
      const float4 s0 = *(const float4*)(scr[t]);
      const float4 s1 = *(const float4*)(scr[t] + 4);
      const float tt = ((s0.x + s0.y) + (s0.z + s0.w)) +
                       ((s1.x + s1.y) + (s1.z + s1.w)) + o3bias;
      prod *= 1.f / (1.f + expf(-tt));
    }
    __syncthreads();  // (e) A' visible

    // ---- M2 (in place)
    zero24(a1, a2);
    lgemm<8>(a1, a2, Xs, WhL + 416 * 64, WlL + 416 * 64, wu, g, s);
    __syncthreads();  // (f) reads done
    epi_write(a1, a2, M2b, Xs, wu, g, s);
    __syncthreads();  // (g)

    // ---- M3 (in place); next-iter sync (a) covers the write->read edge
    zero24(a1, a2);
    lgemm<8>(a1, a2, Xs, WhL + 544 * 64, WlL + 544 * 64, wu, g, s);
    __syncthreads();  // (h) reads done
    epi_write(a1, a2, M3b, Xs, wu, g, s);
  }

  if (t < 64) out[n0 + t] = prod;
}

extern "C" void kernel_launch(void* const* d_in, const int* in_sizes, int n_in,
                              void* d_out, int out_size, void* d_ws, size_t ws_size,
                              hipStream_t stream) {
  const float* towers    = (const float*)d_in[0];
  const float* aggregate = (const float*)d_in[1];
  const float* M1w = (const float*)d_in[2];
  const float* M1b = (const float*)d_in[3];
  const float* M2w = (const float*)d_in[4];
  const float* M2b = (const float*)d_in[5];
  const float* M3w = (const float*)d_in[6];
  const float* M3b = (const float*)d_in[7];
  const float* O1w = (const float*)d_in[8];
  const float* O1b = (const float*)d_in[9];
  const float* O2w = (const float*)d_in[10];
  const float* O2b = (const float*)d_in[11];
  const float* O3w = (const float*)d_in[12];
  const float* O3b = (const float*)d_in[13];
  float* out = (float*)d_out;

  prep_w<<<672, 64, 0, stream>>>(O1w, M1w, O2w, M2w, M3w);

  const int nblocks = out_size / 64;  // 2048 blocks x 512 threads (8 waves)
  topdown_mfma<<<nblocks, 512, 0, stream>>>(towers, aggregate, O1b, O2b, O3w,
                                            O3b, M1b, M2b, M3b, out);
}